// Round 1
// baseline (587.634 us; speedup 1.0000x reference)
//
#include <hip/hip_runtime.h>
#include <hip/hip_bf16.h>
#include <float.h>

#define NEG 0.2f

__device__ __forceinline__ float leaky(float x) { return x > 0.0f ? x : NEG * x; }

// ---------------------------------------------------------------- utilities
__global__ void zero_kernel(int* __restrict__ p, int n) {
  int i = blockIdx.x * blockDim.x + threadIdx.x;
  int stride = gridDim.x * blockDim.x;
  for (; i < n; i += stride) p[i] = 0;
}

__global__ void count_kernel(const int* __restrict__ ei, int* __restrict__ deg, int E, int N) {
  int i = blockIdx.x * blockDim.x + threadIdx.x;
  if (i >= E + N) return;
  int dst = (i < E) ? ei[E + i] : (i - E);
  atomicAdd(&deg[dst], 1);
}

__global__ __launch_bounds__(1024) void scan_block_kernel(const int* __restrict__ deg,
                                                          int* __restrict__ row_start,
                                                          int* __restrict__ sums, int n) {
  __shared__ int buf[1024];
  int t = threadIdx.x;
  int idx = blockIdx.x * 1024 + t;
  int x = (idx < n) ? deg[idx] : 0;
  int v = x;
  buf[t] = v;
  __syncthreads();
  for (int off = 1; off < 1024; off <<= 1) {
    int a = (t >= off) ? buf[t - off] : 0;
    __syncthreads();
    v += a;
    buf[t] = v;
    __syncthreads();
  }
  if (idx < n) row_start[idx] = v - x;  // local exclusive
  if (t == 1023) sums[blockIdx.x] = v;  // chunk total
}

__global__ __launch_bounds__(1024) void scan_sums_kernel(int* __restrict__ sums,
                                                         int* __restrict__ row_start,
                                                         int nch, int n) {
  __shared__ int buf[1024];
  int t = threadIdx.x;
  int x = (t < nch) ? sums[t] : 0;
  int v = x;
  buf[t] = v;
  __syncthreads();
  for (int off = 1; off < 1024; off <<= 1) {
    int a = (t >= off) ? buf[t - off] : 0;
    __syncthreads();
    v += a;
    buf[t] = v;
    __syncthreads();
  }
  if (t < nch) sums[t] = v - x;        // exclusive chunk offsets
  if (t == 1023) row_start[n] = v;     // grand total
}

__global__ __launch_bounds__(1024) void scan_add_kernel(int* __restrict__ row_start,
                                                        const int* __restrict__ sums, int n) {
  int idx = blockIdx.x * 1024 + threadIdx.x;
  if (idx < n) row_start[idx] += sums[blockIdx.x];
}

__global__ void fill_kernel(const int* __restrict__ ei, int* __restrict__ cursor,
                            const int* __restrict__ row_start, int* __restrict__ csr_src,
                            int E, int N) {
  int i = blockIdx.x * blockDim.x + threadIdx.x;
  if (i >= E + N) return;
  int src, dst;
  if (i < E) { src = ei[i]; dst = ei[E + i]; } else { src = dst = i - E; }
  int pos = atomicAdd(&cursor[dst], 1);
  csr_src[row_start[dst] + pos] = src;
}

// ---------------------------------------------------------------- GEMM  H = X @ W   (cols fixed at 128)
__global__ __launch_bounds__(256) void gemm_kernel(const float* __restrict__ X,
                                                   const float* __restrict__ W,
                                                   float* __restrict__ Hout, int nrows, int K) {
  __shared__ float Xs[64][36];    // 64 rows x 32 k, stride 36 (16B aligned, conflict-benign)
  __shared__ float Ws[32][132];   // 32 k x 128 cols, stride 132
  int t = threadIdx.x;
  int row0 = blockIdx.x * 64;
  int tcol = t & 31;   // 32 col-groups of 4 cols
  int trow = t >> 5;   // 8 row-groups; rows trow + 8*i
  float acc[8][4];
#pragma unroll
  for (int i = 0; i < 8; ++i)
#pragma unroll
    for (int j = 0; j < 4; ++j) acc[i][j] = 0.0f;

  for (int kb = 0; kb < K; kb += 32) {
#pragma unroll
    for (int p = 0; p < 2; ++p) {       // X tile: 64x32 = 512 float4
      int flat = t + p * 256;
      int r = flat >> 3;
      int kq = (flat & 7) * 4;
      float4 v = make_float4(0.f, 0.f, 0.f, 0.f);
      int gr = row0 + r;
      if (gr < nrows) v = *(const float4*)(X + (size_t)gr * K + kb + kq);
      *(float4*)(&Xs[r][kq]) = v;
    }
#pragma unroll
    for (int p = 0; p < 4; ++p) {       // W tile: 32x128 = 1024 float4
      int flat = t + p * 256;
      int r = flat >> 5;
      int cq = (flat & 31) * 4;
      float4 v = *(const float4*)(W + (size_t)(kb + r) * 128 + cq);
      *(float4*)(&Ws[r][cq]) = v;
    }
    __syncthreads();
#pragma unroll
    for (int kk = 0; kk < 32; kk += 4) {
      float4 xv[8];
#pragma unroll
      for (int i = 0; i < 8; ++i) xv[i] = *(const float4*)(&Xs[trow + 8 * i][kk]);
#pragma unroll
      for (int q = 0; q < 4; ++q) {
        float4 wv = *(const float4*)(&Ws[kk + q][tcol * 4]);
#pragma unroll
        for (int i = 0; i < 8; ++i) {
          float xq = (q == 0) ? xv[i].x : (q == 1) ? xv[i].y : (q == 2) ? xv[i].z : xv[i].w;
          acc[i][0] += xq * wv.x;
          acc[i][1] += xq * wv.y;
          acc[i][2] += xq * wv.z;
          acc[i][3] += xq * wv.w;
        }
      }
    }
    __syncthreads();
  }
#pragma unroll
  for (int i = 0; i < 8; ++i) {
    int r = row0 + trow + 8 * i;
    if (r < nrows)
      *(float4*)(Hout + (size_t)r * 128 + tcol * 4) =
          make_float4(acc[i][0], acc[i][1], acc[i][2], acc[i][3]);
  }
}

// ---------------------------------------------------------------- per-node attention logits
// alpha_s[n,h] = sum_c H[n,h*32+c]*a_src[h*32+c]  (flat dot restricted to head segments)
__global__ __launch_bounds__(256) void alpha_kernel(const float* __restrict__ H,
                                                    const float* __restrict__ a_src,
                                                    const float* __restrict__ a_dst,
                                                    float* __restrict__ as_out,
                                                    float* __restrict__ ad_out, int N) {
  int wid = threadIdx.x >> 6;
  int lane = threadIdx.x & 63;
  int n = blockIdx.x * 4 + wid;
  if (n >= N) return;
  float2 hv = *(const float2*)(H + (size_t)n * 128 + 2 * lane);
  float2 asv = *(const float2*)(a_src + 2 * lane);
  float2 adv = *(const float2*)(a_dst + 2 * lane);
  float ps = hv.x * asv.x + hv.y * asv.y;
  float pd = hv.x * adv.x + hv.y * adv.y;
#pragma unroll
  for (int off = 1; off < 16; off <<= 1) {   // reduce within 16-lane head group
    ps += __shfl_xor(ps, off);
    pd += __shfl_xor(pd, off);
  }
  if ((lane & 15) == 0) {
    int h = lane >> 4;
    as_out[n * 4 + h] = ps;
    ad_out[n * 4 + h] = pd;
  }
}

// ---------------------------------------------------------------- aggregation: one wave per dst node
template <int POOL>
__global__ __launch_bounds__(256) void agg_kernel(const float* __restrict__ H,
                                                  const float* __restrict__ as_arr,
                                                  const float* __restrict__ ad_arr,
                                                  const int* __restrict__ csr_src,
                                                  const int* __restrict__ row_start,
                                                  const float* __restrict__ bias,
                                                  float* __restrict__ xnext,
                                                  const int* __restrict__ batch,
                                                  float* __restrict__ pooled, int N) {
  int wid = threadIdx.x >> 6;
  int lane = threadIdx.x & 63;
  int n = blockIdx.x * 4 + wid;
  if (n >= N) return;
  int rs = row_start[n], re = row_start[n + 1];
  int head = lane >> 4;
  float4 ad4 = *(const float4*)(ad_arr + (size_t)n * 4);

  // pass 1: per-head max, edges strided across lanes
  float m0 = -FLT_MAX, m1 = -FLT_MAX, m2 = -FLT_MAX, m3 = -FLT_MAX;
  for (int i = rs + lane; i < re; i += 64) {
    int s = csr_src[i];
    float4 a = *(const float4*)(as_arr + (size_t)s * 4);
    m0 = fmaxf(m0, leaky(a.x + ad4.x));
    m1 = fmaxf(m1, leaky(a.y + ad4.y));
    m2 = fmaxf(m2, leaky(a.z + ad4.z));
    m3 = fmaxf(m3, leaky(a.w + ad4.w));
  }
#pragma unroll
  for (int off = 1; off < 64; off <<= 1) {
    m0 = fmaxf(m0, __shfl_xor(m0, off));
    m1 = fmaxf(m1, __shfl_xor(m1, off));
    m2 = fmaxf(m2, __shfl_xor(m2, off));
    m3 = fmaxf(m3, __shfl_xor(m3, off));
  }
  float m_h = head == 0 ? m0 : head == 1 ? m1 : head == 2 ? m2 : m3;
  float ad_h = head == 0 ? ad4.x : head == 1 ? ad4.y : head == 2 ? ad4.z : ad4.w;

  // pass 2: out = (sum ex*h_src)/(sum ex + 1e-16); lane owns channels 2l,2l+1
  const float* hp = H + 2 * lane;
  float denom = 0.f, acc0 = 0.f, acc1 = 0.f;
  int i = rs;
  for (; i + 2 <= re; i += 2) {
    int s0 = csr_src[i], s1 = csr_src[i + 1];
    float a0 = as_arr[(size_t)s0 * 4 + head];
    float a1 = as_arr[(size_t)s1 * 4 + head];
    float2 h0 = *(const float2*)(hp + (size_t)s0 * 128);
    float2 h1 = *(const float2*)(hp + (size_t)s1 * 128);
    float e0 = __expf(leaky(a0 + ad_h) - m_h);
    float e1 = __expf(leaky(a1 + ad_h) - m_h);
    denom += e0 + e1;
    acc0 += e0 * h0.x + e1 * h1.x;
    acc1 += e0 * h0.y + e1 * h1.y;
  }
  if (i < re) {
    int s0 = csr_src[i];
    float a0 = as_arr[(size_t)s0 * 4 + head];
    float2 h0 = *(const float2*)(hp + (size_t)s0 * 128);
    float e0 = __expf(leaky(a0 + ad_h) - m_h);
    denom += e0;
    acc0 += e0 * h0.x;
    acc1 += e0 * h0.y;
  }
  float inv = 1.0f / (denom + 1e-16f);
  float2 bv = *(const float2*)(bias + 2 * lane);
  float v0 = leaky(acc0 * inv + bv.x);
  float v1 = leaky(acc1 * inv + bv.y);
  if (POOL) {
    int g = batch[n];
    atomicAdd(&pooled[(size_t)g * 128 + 2 * lane], v0);
    atomicAdd(&pooled[(size_t)g * 128 + 2 * lane + 1], v1);
  } else {
    *(float2*)(xnext + (size_t)n * 128 + 2 * lane) = make_float2(v0, v1);
  }
}

// ---------------------------------------------------------------- head: out = bn_g*(pooled@fc_w+fc_b)*inv + bn_b
__global__ void head_kernel(const float* __restrict__ pooled, const float* __restrict__ fc_w,
                            const float* __restrict__ fc_b, const float* __restrict__ bn_g,
                            const float* __restrict__ bn_b, float* __restrict__ out, int G) {
  int t = threadIdx.x;
  int g = blockIdx.x * 8 + (t >> 5);
  int j = t & 31;
  if (g >= G) return;
  const float* pr = pooled + (size_t)g * 128;
  float acc = 0.f;
#pragma unroll 8
  for (int k = 0; k < 128; ++k) acc += pr[k] * fc_w[k * 32 + j];
  const float inv = 0.9999950000374997f;  // 1/sqrt(1+1e-5)
  out[g * 32 + j] = bn_g[j] * (acc + fc_b[j]) * inv + bn_b[j];
}

// ---------------------------------------------------------------- launch
extern "C" void kernel_launch(void* const* d_in, const int* in_sizes, int n_in,
                              void* d_out, int out_size, void* d_ws, size_t ws_size,
                              hipStream_t stream) {
  const float* x = (const float*)d_in[0];
  const int* ei = (const int*)d_in[1];
  const int* batch = (const int*)d_in[2];
  const float* Wm[3] = {(const float*)d_in[3], (const float*)d_in[7], (const float*)d_in[11]};
  const float* a_s[3] = {(const float*)d_in[4], (const float*)d_in[8], (const float*)d_in[12]};
  const float* a_d[3] = {(const float*)d_in[5], (const float*)d_in[9], (const float*)d_in[13]};
  const float* bb[3] = {(const float*)d_in[6], (const float*)d_in[10], (const float*)d_in[14]};
  const float* fc_w = (const float*)d_in[15];
  const float* fc_b = (const float*)d_in[16];
  const float* bn_g = (const float*)d_in[17];
  const float* bn_b = (const float*)d_in[18];
  float* out = (float*)d_out;

  int N = in_sizes[0] / 64;
  int E = in_sizes[1] / 2;
  int G = out_size / 32;
  int Etot = E + N;

  char* p = (char*)d_ws;
  auto carve = [&](size_t bytes) {
    char* r = p;
    p += (bytes + 255) & ~size_t(255);
    return r;
  };
  int* deg       = (int*)carve((size_t)N * 4);
  int* cursor    = (int*)carve((size_t)N * 4);
  float* pooled  = (float*)carve((size_t)G * 128 * 4);
  int* row_start = (int*)carve((size_t)(N + 1) * 4);
  int* sums      = (int*)carve(4096);
  int* csr_src   = (int*)carve((size_t)Etot * 4);
  float* bufA    = (float*)carve((size_t)N * 128 * 4);
  float* bufB    = (float*)carve((size_t)N * 128 * 4);
  float* as_arr  = (float*)carve((size_t)N * 4 * 4);
  float* ad_arr  = (float*)carve((size_t)N * 4 * 4);

  // zero deg+cursor+pooled (contiguous carve region, pads included)
  int nz = (int)(((char*)(pooled + (size_t)G * 128) - (char*)deg) / 4);
  zero_kernel<<<512, 256, 0, stream>>>(deg, nz);

  // CSR build (dst-grouped)
  int egrid = (Etot + 255) / 256;
  count_kernel<<<egrid, 256, 0, stream>>>(ei, deg, E, N);
  int nch = (N + 1023) / 1024;
  scan_block_kernel<<<nch, 1024, 0, stream>>>(deg, row_start, sums, N);
  scan_sums_kernel<<<1, 1024, 0, stream>>>(sums, row_start, nch, N);
  scan_add_kernel<<<nch, 1024, 0, stream>>>(row_start, sums, N);
  fill_kernel<<<egrid, 256, 0, stream>>>(ei, cursor, row_start, csr_src, E, N);

  int ggrid = (N + 63) / 64;
  int ngrid = (N + 3) / 4;

  // layer 0 (K=64)
  gemm_kernel<<<ggrid, 256, 0, stream>>>(x, Wm[0], bufB, N, 64);
  alpha_kernel<<<ngrid, 256, 0, stream>>>(bufB, a_s[0], a_d[0], as_arr, ad_arr, N);
  agg_kernel<0><<<ngrid, 256, 0, stream>>>(bufB, as_arr, ad_arr, csr_src, row_start, bb[0],
                                           bufA, nullptr, nullptr, N);
  // layer 1 (K=128)
  gemm_kernel<<<ggrid, 256, 0, stream>>>(bufA, Wm[1], bufB, N, 128);
  alpha_kernel<<<ngrid, 256, 0, stream>>>(bufB, a_s[1], a_d[1], as_arr, ad_arr, N);
  agg_kernel<0><<<ngrid, 256, 0, stream>>>(bufB, as_arr, ad_arr, csr_src, row_start, bb[1],
                                           bufA, nullptr, nullptr, N);
  // layer 2 (K=128), fused pooling
  gemm_kernel<<<ggrid, 256, 0, stream>>>(bufA, Wm[2], bufB, N, 128);
  alpha_kernel<<<ngrid, 256, 0, stream>>>(bufB, a_s[2], a_d[2], as_arr, ad_arr, N);
  agg_kernel<1><<<ngrid, 256, 0, stream>>>(bufB, as_arr, ad_arr, csr_src, row_start, bb[2],
                                           nullptr, batch, pooled, N);

  head_kernel<<<(G + 7) / 8, 256, 0, stream>>>(pooled, fc_w, fc_b, bn_g, bn_b, out, G);
}

// Round 2
// 514.343 us; speedup vs baseline: 1.1425x; 1.1425x over previous
//
#include <hip/hip_runtime.h>
#include <hip/hip_bf16.h>
#include <float.h>

#define NEG 0.2f

__device__ __forceinline__ float leaky(float x) { return x > 0.0f ? x : NEG * x; }

__device__ __forceinline__ unsigned short f2bf(float f) {
  unsigned x = __float_as_uint(f);
  unsigned r = (x + 0x7fffu + ((x >> 16) & 1u)) >> 16;  // round-to-nearest-even
  return (unsigned short)r;
}

__device__ __forceinline__ float2 bf2f2(unsigned u) {   // u = (ch1<<16)|ch0
  float2 r;
  r.x = __uint_as_float(u << 16);
  r.y = __uint_as_float(u & 0xffff0000u);
  return r;
}

// ---------------------------------------------------------------- utilities
__global__ void zero_kernel(int* __restrict__ p, int n) {
  int i = blockIdx.x * blockDim.x + threadIdx.x;
  int stride = gridDim.x * blockDim.x;
  for (; i < n; i += stride) p[i] = 0;
}

__global__ void count_kernel(const int* __restrict__ ei, int* __restrict__ deg, int E, int N) {
  int i = blockIdx.x * blockDim.x + threadIdx.x;
  if (i >= E + N) return;
  int dst = (i < E) ? ei[E + i] : (i - E);
  atomicAdd(&deg[dst], 1);
}

__global__ __launch_bounds__(1024) void scan_block_kernel(const int* __restrict__ deg,
                                                          int* __restrict__ row_start,
                                                          int* __restrict__ sums, int n) {
  __shared__ int buf[1024];
  int t = threadIdx.x;
  int idx = blockIdx.x * 1024 + t;
  int x = (idx < n) ? deg[idx] : 0;
  int v = x;
  buf[t] = v;
  __syncthreads();
  for (int off = 1; off < 1024; off <<= 1) {
    int a = (t >= off) ? buf[t - off] : 0;
    __syncthreads();
    v += a;
    buf[t] = v;
    __syncthreads();
  }
  if (idx < n) row_start[idx] = v - x;  // local exclusive
  if (t == 1023) sums[blockIdx.x] = v;  // chunk total
}

__global__ __launch_bounds__(1024) void scan_sums_kernel(int* __restrict__ sums,
                                                         int* __restrict__ row_start,
                                                         int nch, int n) {
  __shared__ int buf[1024];
  int t = threadIdx.x;
  int x = (t < nch) ? sums[t] : 0;
  int v = x;
  buf[t] = v;
  __syncthreads();
  for (int off = 1; off < 1024; off <<= 1) {
    int a = (t >= off) ? buf[t - off] : 0;
    __syncthreads();
    v += a;
    buf[t] = v;
    __syncthreads();
  }
  if (t < nch) sums[t] = v - x;        // exclusive chunk offsets
  if (t == 1023) row_start[n] = v;     // grand total
}

__global__ __launch_bounds__(1024) void scan_add_kernel(int* __restrict__ row_start,
                                                        const int* __restrict__ sums, int n) {
  int idx = blockIdx.x * 1024 + threadIdx.x;
  if (idx < n) row_start[idx] += sums[blockIdx.x];
}

__global__ void fill_kernel(const int* __restrict__ ei, int* __restrict__ cursor,
                            const int* __restrict__ row_start, int* __restrict__ csr_src,
                            int E, int N) {
  int i = blockIdx.x * blockDim.x + threadIdx.x;
  if (i >= E + N) return;
  int src, dst;
  if (i < E) { src = ei[i]; dst = ei[E + i]; } else { src = dst = i - E; }
  int pos = atomicAdd(&cursor[dst], 1);
  csr_src[row_start[dst] + pos] = src;
}

// ---------------------------------------------------------------- GEMM  Hb = bf16(X @ W), fused alpha dots
// cols fixed at 128; also emits as_arr[n,4], ad_arr[n,4]
__global__ __launch_bounds__(256) void gemm_kernel(const float* __restrict__ X,
                                                   const float* __restrict__ W,
                                                   unsigned short* __restrict__ Hb,
                                                   const float* __restrict__ a_src,
                                                   const float* __restrict__ a_dst,
                                                   float* __restrict__ as_arr,
                                                   float* __restrict__ ad_arr,
                                                   int nrows, int K) {
  __shared__ float Xs[64][36];    // 64 rows x 32 k, stride 36
  __shared__ float Ws[32][132];   // 32 k x 128 cols, stride 132
  int t = threadIdx.x;
  int row0 = blockIdx.x * 64;
  int tcol = t & 31;   // 32 col-groups of 4 cols
  int trow = t >> 5;   // 8 row-groups; rows trow + 8*i
  float acc[8][4];
#pragma unroll
  for (int i = 0; i < 8; ++i)
#pragma unroll
    for (int j = 0; j < 4; ++j) acc[i][j] = 0.0f;

  for (int kb = 0; kb < K; kb += 32) {
#pragma unroll
    for (int p = 0; p < 2; ++p) {       // X tile: 64x32 = 512 float4
      int flat = t + p * 256;
      int r = flat >> 3;
      int kq = (flat & 7) * 4;
      float4 v = make_float4(0.f, 0.f, 0.f, 0.f);
      int gr = row0 + r;
      if (gr < nrows) v = *(const float4*)(X + (size_t)gr * K + kb + kq);
      *(float4*)(&Xs[r][kq]) = v;
    }
#pragma unroll
    for (int p = 0; p < 4; ++p) {       // W tile: 32x128 = 1024 float4
      int flat = t + p * 256;
      int r = flat >> 5;
      int cq = (flat & 31) * 4;
      float4 v = *(const float4*)(W + (size_t)(kb + r) * 128 + cq);
      *(float4*)(&Ws[r][cq]) = v;
    }
    __syncthreads();
#pragma unroll
    for (int kk = 0; kk < 32; kk += 4) {
      float4 xv[8];
#pragma unroll
      for (int i = 0; i < 8; ++i) xv[i] = *(const float4*)(&Xs[trow + 8 * i][kk]);
#pragma unroll
      for (int q = 0; q < 4; ++q) {
        float4 wv = *(const float4*)(&Ws[kk + q][tcol * 4]);
#pragma unroll
        for (int i = 0; i < 8; ++i) {
          float xq = (q == 0) ? xv[i].x : (q == 1) ? xv[i].y : (q == 2) ? xv[i].z : xv[i].w;
          acc[i][0] += xq * wv.x;
          acc[i][1] += xq * wv.y;
          acc[i][2] += xq * wv.z;
          acc[i][3] += xq * wv.w;
        }
      }
    }
    __syncthreads();
  }

  // store bf16 H + fused per-head alpha dots
  float4 as4 = *(const float4*)(a_src + tcol * 4);
  float4 ad4 = *(const float4*)(a_dst + tcol * 4);
  float ps[8], pd[8];
#pragma unroll
  for (int i = 0; i < 8; ++i) {
    int r = row0 + trow + 8 * i;
    if (r < nrows) {
      union { unsigned short u[4]; uint2 v; } pk;
      pk.u[0] = f2bf(acc[i][0]);
      pk.u[1] = f2bf(acc[i][1]);
      pk.u[2] = f2bf(acc[i][2]);
      pk.u[3] = f2bf(acc[i][3]);
      *(uint2*)(Hb + (size_t)r * 128 + tcol * 4) = pk.v;
    }
    ps[i] = acc[i][0] * as4.x + acc[i][1] * as4.y + acc[i][2] * as4.z + acc[i][3] * as4.w;
    pd[i] = acc[i][0] * ad4.x + acc[i][1] * ad4.y + acc[i][2] * ad4.z + acc[i][3] * ad4.w;
  }
  // reduce over the 8 tcols of each head (xor offsets 1,2,4 stay in head group & same trow)
#pragma unroll
  for (int off = 1; off < 8; off <<= 1) {
#pragma unroll
    for (int i = 0; i < 8; ++i) {
      ps[i] += __shfl_xor(ps[i], off);
      pd[i] += __shfl_xor(pd[i], off);
    }
  }
  if ((tcol & 7) == 0) {
    int head = tcol >> 3;
#pragma unroll
    for (int i = 0; i < 8; ++i) {
      int r = row0 + trow + 8 * i;
      if (r < nrows) {
        as_arr[(size_t)r * 4 + head] = ps[i];
        ad_arr[(size_t)r * 4 + head] = pd[i];
      }
    }
  }
}

// ---------------------------------------------------------------- aggregation: one wave per dst node, single pass
// softmax without max-subtraction (logits are O(1); clamp at 80 for paranoia)
template <int POOL>
__global__ __launch_bounds__(256) void agg_kernel(const unsigned short* __restrict__ Hb,
                                                  const float* __restrict__ as_arr,
                                                  const float* __restrict__ ad_arr,
                                                  const int* __restrict__ csr_src,
                                                  const int* __restrict__ row_start,
                                                  const float* __restrict__ bias,
                                                  float* __restrict__ xnext,
                                                  const int* __restrict__ batch,
                                                  float* __restrict__ pooled, int N) {
  int wid = threadIdx.x >> 6;
  int lane = threadIdx.x & 63;
  int n = blockIdx.x * 4 + wid;
  if (n >= N) return;
  int rs = row_start[n], re = row_start[n + 1];
  int head = lane >> 4;
  float ad_h = ad_arr[(size_t)n * 4 + head];

  const unsigned* hp = (const unsigned*)Hb + lane;  // lane owns packed channels 2l,2l+1
  float denom = 0.f, acc0 = 0.f, acc1 = 0.f;
  int i = rs;
  for (; i + 2 <= re; i += 2) {
    int s0 = csr_src[i], s1 = csr_src[i + 1];
    float a0 = as_arr[(size_t)s0 * 4 + head];
    float a1 = as_arr[(size_t)s1 * 4 + head];
    unsigned u0 = hp[(size_t)s0 * 64];
    unsigned u1 = hp[(size_t)s1 * 64];
    float e0 = __expf(fminf(leaky(a0 + ad_h), 80.f));
    float e1 = __expf(fminf(leaky(a1 + ad_h), 80.f));
    float2 h0 = bf2f2(u0);
    float2 h1 = bf2f2(u1);
    denom += e0 + e1;
    acc0 += e0 * h0.x + e1 * h1.x;
    acc1 += e0 * h0.y + e1 * h1.y;
  }
  if (i < re) {
    int s0 = csr_src[i];
    float a0 = as_arr[(size_t)s0 * 4 + head];
    unsigned u0 = hp[(size_t)s0 * 64];
    float e0 = __expf(fminf(leaky(a0 + ad_h), 80.f));
    float2 h0 = bf2f2(u0);
    denom += e0;
    acc0 += e0 * h0.x;
    acc1 += e0 * h0.y;
  }
  float inv = 1.0f / (denom + 1e-16f);
  float2 bv = *(const float2*)(bias + 2 * lane);
  float v0 = leaky(acc0 * inv + bv.x);
  float v1 = leaky(acc1 * inv + bv.y);
  if (POOL) {
    int g = batch[n];
    atomicAdd(&pooled[(size_t)g * 128 + 2 * lane], v0);
    atomicAdd(&pooled[(size_t)g * 128 + 2 * lane + 1], v1);
  } else {
    *(float2*)(xnext + (size_t)n * 128 + 2 * lane) = make_float2(v0, v1);
  }
}

// ---------------------------------------------------------------- head: out = bn_g*(pooled@fc_w+fc_b)*inv + bn_b
__global__ void head_kernel(const float* __restrict__ pooled, const float* __restrict__ fc_w,
                            const float* __restrict__ fc_b, const float* __restrict__ bn_g,
                            const float* __restrict__ bn_b, float* __restrict__ out, int G) {
  int t = threadIdx.x;
  int g = blockIdx.x * 8 + (t >> 5);
  int j = t & 31;
  if (g >= G) return;
  const float* pr = pooled + (size_t)g * 128;
  float acc = 0.f;
#pragma unroll 8
  for (int k = 0; k < 128; ++k) acc += pr[k] * fc_w[k * 32 + j];
  const float inv = 0.9999950000374997f;  // 1/sqrt(1+1e-5)
  out[g * 32 + j] = bn_g[j] * (acc + fc_b[j]) * inv + bn_b[j];
}

// ---------------------------------------------------------------- launch
extern "C" void kernel_launch(void* const* d_in, const int* in_sizes, int n_in,
                              void* d_out, int out_size, void* d_ws, size_t ws_size,
                              hipStream_t stream) {
  const float* x = (const float*)d_in[0];
  const int* ei = (const int*)d_in[1];
  const int* batch = (const int*)d_in[2];
  const float* Wm[3] = {(const float*)d_in[3], (const float*)d_in[7], (const float*)d_in[11]};
  const float* a_s[3] = {(const float*)d_in[4], (const float*)d_in[8], (const float*)d_in[12]};
  const float* a_d[3] = {(const float*)d_in[5], (const float*)d_in[9], (const float*)d_in[13]};
  const float* bb[3] = {(const float*)d_in[6], (const float*)d_in[10], (const float*)d_in[14]};
  const float* fc_w = (const float*)d_in[15];
  const float* fc_b = (const float*)d_in[16];
  const float* bn_g = (const float*)d_in[17];
  const float* bn_b = (const float*)d_in[18];
  float* out = (float*)d_out;

  int N = in_sizes[0] / 64;
  int E = in_sizes[1] / 2;
  int G = out_size / 32;
  int Etot = E + N;

  char* p = (char*)d_ws;
  auto carve = [&](size_t bytes) {
    char* r = p;
    p += (bytes + 255) & ~size_t(255);
    return r;
  };
  int* deg       = (int*)carve((size_t)N * 4);
  int* cursor    = (int*)carve((size_t)N * 4);
  float* pooled  = (float*)carve((size_t)G * 128 * 4);
  int* row_start = (int*)carve((size_t)(N + 1) * 4);
  int* sums      = (int*)carve(4096);
  int* csr_src   = (int*)carve((size_t)Etot * 4);
  unsigned short* Hb = (unsigned short*)carve((size_t)N * 128 * 2);  // bf16 features
  float* bufX    = (float*)carve((size_t)N * 128 * 4);               // fp32 layer input
  float* as_arr  = (float*)carve((size_t)N * 4 * 4);
  float* ad_arr  = (float*)carve((size_t)N * 4 * 4);

  // zero deg+cursor+pooled (contiguous carve region, pads included)
  int nz = (int)(((char*)(pooled + (size_t)G * 128) - (char*)deg) / 4);
  zero_kernel<<<512, 256, 0, stream>>>(deg, nz);

  // CSR build (dst-grouped)
  int egrid = (Etot + 255) / 256;
  count_kernel<<<egrid, 256, 0, stream>>>(ei, deg, E, N);
  int nch = (N + 1023) / 1024;
  scan_block_kernel<<<nch, 1024, 0, stream>>>(deg, row_start, sums, N);
  scan_sums_kernel<<<1, 1024, 0, stream>>>(sums, row_start, nch, N);
  scan_add_kernel<<<nch, 1024, 0, stream>>>(row_start, sums, N);
  fill_kernel<<<egrid, 256, 0, stream>>>(ei, cursor, row_start, csr_src, E, N);

  int ggrid = (N + 63) / 64;
  int ngrid = (N + 3) / 4;

  // layer 0 (K=64)
  gemm_kernel<<<ggrid, 256, 0, stream>>>(x, Wm[0], Hb, a_s[0], a_d[0], as_arr, ad_arr, N, 64);
  agg_kernel<0><<<ngrid, 256, 0, stream>>>(Hb, as_arr, ad_arr, csr_src, row_start, bb[0],
                                           bufX, nullptr, nullptr, N);
  // layer 1 (K=128)
  gemm_kernel<<<ggrid, 256, 0, stream>>>(bufX, Wm[1], Hb, a_s[1], a_d[1], as_arr, ad_arr, N, 128);
  agg_kernel<0><<<ngrid, 256, 0, stream>>>(Hb, as_arr, ad_arr, csr_src, row_start, bb[1],
                                           bufX, nullptr, nullptr, N);
  // layer 2 (K=128), fused pooling
  gemm_kernel<<<ggrid, 256, 0, stream>>>(bufX, Wm[2], Hb, a_s[2], a_d[2], as_arr, ad_arr, N, 128);
  agg_kernel<1><<<ngrid, 256, 0, stream>>>(Hb, as_arr, ad_arr, csr_src, row_start, bb[2],
                                           nullptr, batch, pooled, N);

  head_kernel<<<(G + 7) / 8, 256, 0, stream>>>(pooled, fc_w, fc_b, bn_g, bn_b, out, G);
}